// Round 8
// baseline (32.634 us; speedup 1.0000x reference)
//
#include <hip/hip_runtime.h>

#define AR 8
#define SEQ 4096
#define BATCH 8192
#define OUTW (AR + SEQ)   // 4104 floats per output row
#define NB 1024           // blocks; each owns BATCH/NB = 8 rows

typedef float f32x4 __attribute__((ext_vector_type(4)));

// ---------------- Fused, row-contiguous stores ----------------
// A = companion (row-vector convention): (R*A)_j = R_{j-1} + R_7 * w_j.
// Block: LDS table P[k]=A^(2^k). Thread: 16 C-rows in regs for
// t in {4*tid+k + 1024*s : k=0..3, s=0..3}. Per row-iteration the block writes
// one ENTIRE output row (16.4 KB) contiguously: thread tid stores pred-f32x4
// slots tid+256*s (lane-contiguous 1KB bursts; block sequential 16KB; grid
// window ~16.8MB). Plain cached stores (NT: 1.78x amplification R3, -5us R5).
__global__ __launch_bounds__(256, 2) void arx_fused_kernel(const float* __restrict__ y,
                                                           const float* __restrict__ W,
                                                           float* __restrict__ out) {
    __shared__ float P[12][AR][AR];   // P[k] = A^(2^k), 3 KB
    __shared__ float w[AR];
    const int tid = threadIdx.x;

    if (tid < AR) w[tid] = W[tid];
    __syncthreads();

    if (tid < 64) {
        const int i = tid >> 3, j = tid & 7;
        P[0][i][j] = (i == 7) ? w[j] : ((i == j - 1) ? 1.f : 0.f);
    }
    __syncthreads();

    for (int k = 0; k < 11; ++k) {
        if (tid < 64) {
            const int i = tid >> 3, j = tid & 7;
            float v = 0.f;
            #pragma unroll
            for (int q = 0; q < AR; ++q) v += P[k][i][q] * P[k][q][j];
            P[k + 1][i][j] = v;
        }
        __syncthreads();
    }

    // ---- 16 C-rows per thread: c[4s+k] = row for t = 4*tid + k + 1024*s ----
    float c[16][AR];
    {
        const int t0 = tid * 4;                 // bits 2..9 only
        float r[AR];
        #pragma unroll
        for (int j = 0; j < AR; ++j) r[j] = w[j];
        #pragma unroll
        for (int k = 2; k < 10; ++k) {
            if ((t0 >> k) & 1) {
                float nr[AR];
                #pragma unroll
                for (int j = 0; j < AR; ++j) {
                    float s = 0.f;
                    #pragma unroll
                    for (int q = 0; q < AR; ++q) s += r[q] * P[k][q][j];
                    nr[j] = s;
                }
                #pragma unroll
                for (int j = 0; j < AR; ++j) r[j] = nr[j];
            }
        }
        #pragma unroll
        for (int j = 0; j < AR; ++j) c[0][j] = r[j];
        #pragma unroll
        for (int k = 1; k < 4; ++k) {           // companion advances t -> t+1
            const float c7 = c[k - 1][AR - 1];
            c[k][0] = c7 * w[0];
            #pragma unroll
            for (int j = 1; j < AR; ++j) c[k][j] = c[k - 1][j - 1] + c7 * w[j];
        }
        #pragma unroll
        for (int k = 0; k < 4; ++k) {           // +1024 : * P[10]
            #pragma unroll
            for (int j = 0; j < AR; ++j) {
                float s = 0.f;
                #pragma unroll
                for (int q = 0; q < AR; ++q) s += c[k][q] * P[10][q][j];
                c[4 + k][j] = s;
            }
        }
        #pragma unroll
        for (int k = 0; k < 4; ++k) {           // +2048 : * P[11]
            #pragma unroll
            for (int j = 0; j < AR; ++j) {
                float s = 0.f;
                #pragma unroll
                for (int q = 0; q < AR; ++q) s += c[k][q] * P[11][q][j];
                c[8 + k][j] = s;
            }
        }
        #pragma unroll
        for (int k = 0; k < 4; ++k) {           // +3072 : (+1024) * P[11]
            #pragma unroll
            for (int j = 0; j < AR; ++j) {
                float s = 0.f;
                #pragma unroll
                for (int q = 0; q < AR; ++q) s += c[4 + k][q] * P[11][q][j];
                c[12 + k][j] = s;
            }
        }
    }

    // ---- row loop: block b handles rows b, b+NB, ... (global sliding window) ----
    for (int row = blockIdx.x; row < BATCH; row += NB) {
        const f32x4* yv = reinterpret_cast<const f32x4*>(y + (size_t)row * AR);
        const f32x4 a = yv[0], b = yv[1];
        const float yy[AR] = {a.x, a.y, a.z, a.w, b.x, b.y, b.z, b.w};

        float* rowp = out + (size_t)row * OUTW;

        // head: first 8 floats = y row
        if (tid < 2) reinterpret_cast<f32x4*>(rowp)[tid] = (tid == 0) ? a : b;

        f32x4* pred = reinterpret_cast<f32x4*>(rowp + AR);
        #pragma unroll
        for (int s = 0; s < 4; ++s) {
            float v[4];
            #pragma unroll
            for (int k = 0; k < 4; ++k) {
                float acc = 0.f;
                #pragma unroll
                for (int j = 0; j < AR; ++j) acc += c[4 * s + k][j] * yy[j];
                v[k] = acc;
            }
            pred[tid + 256 * s] = (f32x4){v[0], v[1], v[2], v[3]};
        }
    }
}

extern "C" void kernel_launch(void* const* d_in, const int* in_sizes, int n_in,
                              void* d_out, int out_size, void* d_ws, size_t ws_size,
                              hipStream_t stream) {
    const float* y = (const float*)d_in[0];
    // d_in[1] = u  -- unused by the reference computation
    const float* W = (const float*)d_in[2];
    float* out = (float*)d_out;

    arx_fused_kernel<<<NB, 256, 0, stream>>>(y, W, out);
}

// Round 9
// 28.762 us; speedup vs baseline: 1.1346x; 1.1346x over previous
//
#include <hip/hip_runtime.h>

#define AR 8
#define SEQ 4096
#define BATCH 8192
#define OUTW (AR + SEQ)   // 4104 floats per output row

typedef float f32x4 __attribute__((ext_vector_type(4)));

// ---------------- Fused: out = [y | y @ C^T] with C derived in-block ----------------
// R7 structure (best: 27.5us) + y-prefetch pipeline + 2048 blocks.
// A = companion (row-vector convention): (R*A)_j = R_{j-1} + R_7 * w_j.
// Per block: LDS table P[k]=A^(2^k) (11 cooperative 8x8 squarings, ~0.5us).
// Per thread: 4 C-rows in regs via binary decomposition of t0 + 3 companion advances.
// Stores: one f32x4/lane, lanes contiguous (1KB/wave, full 64B lines), plain cached
// (NT: 1.78x write amplification at strided lanes [R3], -5us even full-line [R5]).
__global__ __launch_bounds__(256, 4) void arx_fused_kernel(const float* __restrict__ y,
                                                           const float* __restrict__ W,
                                                           float* __restrict__ out) {
    __shared__ float P[12][AR][AR];   // P[k] = A^(2^k), 3 KB
    __shared__ float w[AR];
    const int tid = threadIdx.x;

    if (tid < AR) w[tid] = W[tid];
    __syncthreads();

    if (tid < 64) {
        const int i = tid >> 3, j = tid & 7;
        P[0][i][j] = (i == 7) ? w[j] : ((i == j - 1) ? 1.f : 0.f);
    }
    __syncthreads();

    for (int k = 0; k < 11; ++k) {
        if (tid < 64) {
            const int i = tid >> 3, j = tid & 7;
            float v = 0.f;
            #pragma unroll
            for (int q = 0; q < AR; ++q) v += P[k][i][q] * P[k][q][j];
            P[k + 1][i][j] = v;
        }
        __syncthreads();
    }

    // Per-thread 4 C-rows in registers.
    const int tt = blockIdx.x * 256 + tid;   // f32x4-group along t: 0..1023
    const int t0 = tt * 4;

    float c[4][AR];
    {
        float r[AR];
        #pragma unroll
        for (int j = 0; j < AR; ++j) r[j] = w[j];          // C[0] = w^T
        #pragma unroll
        for (int k = 2; k < 12; ++k) {                     // t0 has bits >= 2 only
            if ((t0 >> k) & 1) {
                float nr[AR];
                #pragma unroll
                for (int j = 0; j < AR; ++j) {
                    float s = 0.f;
                    #pragma unroll
                    for (int q = 0; q < AR; ++q) s += r[q] * P[k][q][j];
                    nr[j] = s;
                }
                #pragma unroll
                for (int j = 0; j < AR; ++j) r[j] = nr[j];
            }
        }
        #pragma unroll
        for (int j = 0; j < AR; ++j) c[0][j] = r[j];
        #pragma unroll
        for (int k = 1; k < 4; ++k) {                      // companion advances
            const float c7 = c[k - 1][AR - 1];
            c[k][0] = c7 * w[0];
            #pragma unroll
            for (int j = 1; j < AR; ++j) c[k][j] = c[k - 1][j - 1] + c7 * w[j];
        }
    }

    const int RGN = BATCH / 8;            // 1024 row-groups
    int rg = blockIdx.y;

    // Prefetch first row-group's y (block-uniform addresses -> scalar loads).
    float yy[8][AR];
    #pragma unroll
    for (int r = 0; r < 8; ++r) {
        const f32x4* yv = reinterpret_cast<const f32x4*>(y + (size_t)(rg * 8 + r) * AR);
        f32x4 a = yv[0], b = yv[1];
        yy[r][0] = a.x; yy[r][1] = a.y; yy[r][2] = a.z; yy[r][3] = a.w;
        yy[r][4] = b.x; yy[r][5] = b.y; yy[r][6] = b.z; yy[r][7] = b.w;
    }

    for (; rg < RGN; ) {
        const int row0 = rg * 8;
        const int rg_next = rg + gridDim.y;

        // Issue next iteration's y loads before compute/stores (latency hidden).
        f32x4 na[8], nb[8];
        if (rg_next < RGN) {
            #pragma unroll
            for (int r = 0; r < 8; ++r) {
                const f32x4* yv =
                    reinterpret_cast<const f32x4*>(y + (size_t)(rg_next * 8 + r) * AR);
                na[r] = yv[0]; nb[r] = yv[1];
            }
        }

        #pragma unroll
        for (int r = 0; r < 8; ++r) {
            float s[4];
            #pragma unroll
            for (int k = 0; k < 4; ++k) {
                float acc = 0.f;
                #pragma unroll
                for (int j = 0; j < AR; ++j) acc += c[k][j] * yy[r][j];
                s[k] = acc;
            }
            *reinterpret_cast<f32x4*>(out + (size_t)(row0 + r) * OUTW + AR + t0) =
                (f32x4){s[0], s[1], s[2], s[3]};
        }

        // y-head (first 8 output columns) once per row.
        if (blockIdx.x == 0 && threadIdx.x < 16) {
            const int r = threadIdx.x >> 1, part = threadIdx.x & 1;
            const int row = row0 + r;
            reinterpret_cast<f32x4*>(out + (size_t)row * OUTW)[part] =
                reinterpret_cast<const f32x4*>(y + (size_t)row * AR)[part];
        }

        // Commit prefetched y.
        if (rg_next < RGN) {
            #pragma unroll
            for (int r = 0; r < 8; ++r) {
                yy[r][0] = na[r].x; yy[r][1] = na[r].y; yy[r][2] = na[r].z; yy[r][3] = na[r].w;
                yy[r][4] = nb[r].x; yy[r][5] = nb[r].y; yy[r][6] = nb[r].z; yy[r][7] = nb[r].w;
            }
        }
        rg = rg_next;
    }
}

extern "C" void kernel_launch(void* const* d_in, const int* in_sizes, int n_in,
                              void* d_out, int out_size, void* d_ws, size_t ws_size,
                              hipStream_t stream) {
    const float* y = (const float*)d_in[0];
    // d_in[1] = u  -- unused by the reference computation
    const float* W = (const float*)d_in[2];
    float* out = (float*)d_out;

    arx_fused_kernel<<<dim3(SEQ / 1024, 512), 256, 0, stream>>>(y, W, out);
}

// Round 10
// 27.393 us; speedup vs baseline: 1.1913x; 1.0500x over previous
//
#include <hip/hip_runtime.h>

#define AR 8
#define SEQ 4096
#define BATCH 8192
#define OUTW (AR + SEQ)   // 4104 floats per output row

typedef float f32x4 __attribute__((ext_vector_type(4)));

// ---------------- Fused: out = [y | y @ C^T] with C derived in-block ----------------
// A = companion matrix (row-vector convention): (R*A)_j = R_{j-1} + R_7 * w_j.
// Per block: LDS table P[k] = A^(2^k), k=0..11 (11 cooperative 8x8 squarings).
// Per thread: C-row for t0 = 4*(bx*256+tid) via binary decomposition (bits 2..11),
// then +1,+2,+3 via companion advance. C lives only in registers -- no global C.
// Stores: one f32x4 per lane, lanes contiguous (1KB/wave full-line bursts), cached
// (NT measured 1.78x write amplification at 32B lane stride in R3 and -5us even with
// full lines in R5 -- do not use NT for this on gfx950).
// Best-measured configuration (R7: 27.5us). R8 row-contiguous and R9 prefetch/512-grid
// variants both regressed; 6 store organizations pinned at ~5 TB/s effective ->
// L3-dirty-rewrite store-path ceiling for this 134.5MB L3-resident output.
__global__ __launch_bounds__(256, 4) void arx_fused_kernel(const float* __restrict__ y,
                                                           const float* __restrict__ W,
                                                           float* __restrict__ out) {
    __shared__ float P[12][AR][AR];   // P[k] = A^(2^k), 3 KB
    __shared__ float w[AR];
    const int tid = threadIdx.x;

    if (tid < AR) w[tid] = W[tid];
    __syncthreads();

    if (tid < 64) {
        const int i = tid >> 3, j = tid & 7;
        P[0][i][j] = (i == 7) ? w[j] : ((i == j - 1) ? 1.f : 0.f);
    }
    __syncthreads();

    // Cooperative squaring chain: P[k+1] = P[k] * P[k]
    for (int k = 0; k < 11; ++k) {
        if (tid < 64) {
            const int i = tid >> 3, j = tid & 7;
            float v = 0.f;
            #pragma unroll
            for (int q = 0; q < AR; ++q) v += P[k][i][q] * P[k][q][j];
            P[k + 1][i][j] = v;       // distinct array from P[k]
        }
        __syncthreads();
    }

    // Per-thread 4 C-rows in registers.
    const int tt = blockIdx.x * 256 + tid;   // f32x4-group along t: 0..1023
    const int t0 = tt * 4;

    float c[4][AR];
    {
        float r[AR];
        #pragma unroll
        for (int j = 0; j < AR; ++j) r[j] = w[j];          // C[0] = w^T
        #pragma unroll
        for (int k = 2; k < 12; ++k) {                     // t0 has bits >= 2 only
            if ((t0 >> k) & 1) {
                float nr[AR];
                #pragma unroll
                for (int j = 0; j < AR; ++j) {
                    float s = 0.f;
                    #pragma unroll
                    for (int q = 0; q < AR; ++q) s += r[q] * P[k][q][j];
                    nr[j] = s;
                }
                #pragma unroll
                for (int j = 0; j < AR; ++j) r[j] = nr[j];
            }
        }
        #pragma unroll
        for (int j = 0; j < AR; ++j) c[0][j] = r[j];
        #pragma unroll
        for (int k = 1; k < 4; ++k) {                      // companion advances
            const float c7 = c[k - 1][AR - 1];
            c[k][0] = c7 * w[0];
            #pragma unroll
            for (int j = 1; j < AR; ++j) c[k][j] = c[k - 1][j - 1] + c7 * w[j];
        }
    }

    // Grid-stride over row-groups; C tile stays in registers.
    for (int rg = blockIdx.y; rg < BATCH / 8; rg += gridDim.y) {
        const int row0 = rg * 8;

        // Hoist all 8 y-rows (block-uniform addresses -> scalar loads).
        float yy[8][AR];
        #pragma unroll
        for (int r = 0; r < 8; ++r) {
            const f32x4* yv = reinterpret_cast<const f32x4*>(y + (size_t)(row0 + r) * AR);
            f32x4 a = yv[0], b = yv[1];
            yy[r][0] = a.x; yy[r][1] = a.y; yy[r][2] = a.z; yy[r][3] = a.w;
            yy[r][4] = b.x; yy[r][5] = b.y; yy[r][6] = b.z; yy[r][7] = b.w;
        }

        #pragma unroll
        for (int r = 0; r < 8; ++r) {
            float s[4];
            #pragma unroll
            for (int k = 0; k < 4; ++k) {
                float acc = 0.f;
                #pragma unroll
                for (int j = 0; j < AR; ++j) acc += c[k][j] * yy[r][j];
                s[k] = acc;
            }
            *reinterpret_cast<f32x4*>(out + (size_t)(row0 + r) * OUTW + AR + t0) =
                (f32x4){s[0], s[1], s[2], s[3]};
        }

        // y-head (first 8 output columns) once per row.
        if (blockIdx.x == 0 && threadIdx.x < 16) {
            const int r = threadIdx.x >> 1, part = threadIdx.x & 1;
            const int row = row0 + r;
            reinterpret_cast<f32x4*>(out + (size_t)row * OUTW)[part] =
                reinterpret_cast<const f32x4*>(y + (size_t)row * AR)[part];
        }
    }
}

extern "C" void kernel_launch(void* const* d_in, const int* in_sizes, int n_in,
                              void* d_out, int out_size, void* d_ws, size_t ws_size,
                              hipStream_t stream) {
    const float* y = (const float*)d_in[0];
    // d_in[1] = u  -- unused by the reference computation
    const float* W = (const float*)d_in[2];
    float* out = (float*)d_out;

    arx_fused_kernel<<<dim3(SEQ / 1024, 256), 256, 0, stream>>>(y, W, out);
}